// Round 1
// baseline (346.117 us; speedup 1.0000x reference)
//
#include <hip/hip_runtime.h>

// CSR SpMV: y[r] = sum_{j in [ro[r], ro[r+1])} sx[j] * x[sel[j]]
// NNZ = 32M, ROWS = 1M (+1 offsets), COLS = 1M.
// Nonzero-centric: each thread owns ITEMS contiguous nnz, binary-searches its
// starting row once, walks the chunk, atomicAdd-flushes partial row sums.

constexpr int ITEMS = 16;  // nnz per thread (64B sx + 64B sel per thread)

__global__ __launch_bounds__(256) void zero_out(float* __restrict__ y, int n) {
    int i = blockIdx.x * blockDim.x + threadIdx.x;
    if (i < n) y[i] = 0.0f;
}

__global__ __launch_bounds__(256) void spmv_chunk(
    const float* __restrict__ sx,
    const float* __restrict__ x,
    const int*   __restrict__ sel,
    const int*   __restrict__ ro,   // length num_rows+1, ro[0]=0, ro[nr]=nnz
    float*       __restrict__ y,
    int nnz, int num_rows)
{
    int tid = blockIdx.x * blockDim.x + threadIdx.x;
    int j0  = tid * ITEMS;
    if (j0 >= nnz) return;
    int j1  = min(nnz, j0 + ITEMS);

    // upper_bound: first idx in [1, num_rows] with ro[idx] > j0; row = idx-1.
    // (ro[0]=0 <= j0 always; ro[num_rows]=nnz > j0 always.)
    int left = 1, right = num_rows;
    while (left < right) {
        int mid = (left + right) >> 1;
        if (ro[mid] <= j0) left = mid + 1; else right = mid;
    }
    int r       = left - 1;
    int row_end = ro[r + 1];

    float sum = 0.0f;

    if (j1 - j0 == ITEMS) {
        // full chunk: vectorized 16B loads, 4 groups of 4
        #pragma unroll
        for (int v = 0; v < ITEMS / 4; ++v) {
            const float4 s4 = *reinterpret_cast<const float4*>(sx  + j0 + v * 4);
            const int4   c4 = *reinterpret_cast<const int4*>  (sel + j0 + v * 4);
            float p0 = s4.x * x[c4.x];
            float p1 = s4.y * x[c4.y];
            float p2 = s4.z * x[c4.z];
            float p3 = s4.w * x[c4.w];
            float p[4] = {p0, p1, p2, p3};
            #pragma unroll
            for (int k = 0; k < 4; ++k) {
                int jj = j0 + v * 4 + k;
                while (jj >= row_end) {           // flush row(s); handles empty rows
                    if (sum != 0.0f) atomicAdd(&y[r], sum);
                    sum = 0.0f;
                    ++r;
                    row_end = ro[r + 1];
                }
                sum += p[k];
            }
        }
    } else {
        for (int j = j0; j < j1; ++j) {
            while (j >= row_end) {
                if (sum != 0.0f) atomicAdd(&y[r], sum);
                sum = 0.0f;
                ++r;
                row_end = ro[r + 1];
            }
            sum += sx[j] * x[sel[j]];
        }
    }
    if (sum != 0.0f) atomicAdd(&y[r], sum);
}

extern "C" void kernel_launch(void* const* d_in, const int* in_sizes, int n_in,
                              void* d_out, int out_size, void* d_ws, size_t ws_size,
                              hipStream_t stream) {
    const float* sx  = (const float*)d_in[0];
    const float* x   = (const float*)d_in[1];
    // d_in[2] is the zero "y" input — unused; we zero d_out ourselves.
    const int*   sel = (const int*)d_in[3];
    const int*   ro  = (const int*)d_in[4];
    float*       y   = (float*)d_out;

    const int nnz      = in_sizes[0];
    const int num_rows = in_sizes[4] - 1;   // == out_size

    {
        int threads = 256;
        int blocks  = (out_size + threads - 1) / threads;
        zero_out<<<blocks, threads, 0, stream>>>(y, out_size);
    }
    {
        int threads    = 256;
        long long work = ((long long)nnz + ITEMS - 1) / ITEMS;
        int blocks     = (int)((work + threads - 1) / threads);
        spmv_chunk<<<blocks, threads, 0, stream>>>(sx, x, sel, ro, y, nnz, num_rows);
    }
}

// Round 2
// 288.114 us; speedup vs baseline: 1.2013x; 1.2013x over previous
//
#include <hip/hip_runtime.h>

// CSR SpMV: y[r] = sum_{j in [ro[r], ro[r+1])} sx[j] * x[sel[j]]
// NNZ = 32M, ROWS = 1M (+1 offsets), COLS = 1M.
// Nonzero-centric: each thread owns ITEMS contiguous nnz, binary-searches its
// starting row once, walks the chunk, atomicAdd-flushes partial row sums.
//
// R2 changes vs R1 (346us, FETCH 1.08GB = 4x mandatory):
//  - sx/sel read with __builtin_nontemporal_load (nt flag) so the read-once
//    streams don't evict the 4MB x vector from per-XCD L2 (gathers were ~50%
//    L2-miss -> 1GB line-granularity refetch).
//  - all 16 gathers issued before the row-walk accumulation (was interleaved
//    with atomic flushes -> serialized behind the sum dependency chain).

constexpr int ITEMS = 16;  // nnz per thread (64B sx + 64B sel per thread)

typedef float f32x4 __attribute__((ext_vector_type(4)));
typedef int   i32x4 __attribute__((ext_vector_type(4)));

__global__ __launch_bounds__(256) void zero_out(float* __restrict__ y, int n) {
    int i = blockIdx.x * blockDim.x + threadIdx.x;
    if (i < n) y[i] = 0.0f;
}

__global__ __launch_bounds__(256) void spmv_chunk(
    const float* __restrict__ sx,
    const float* __restrict__ x,
    const int*   __restrict__ sel,
    const int*   __restrict__ ro,   // length num_rows+1, ro[0]=0, ro[nr]=nnz
    float*       __restrict__ y,
    int nnz, int num_rows)
{
    int tid = blockIdx.x * blockDim.x + threadIdx.x;
    int j0  = tid * ITEMS;
    if (j0 >= nnz) return;
    int j1  = min(nnz, j0 + ITEMS);

    // upper_bound: first idx in [1, num_rows] with ro[idx] > j0; row = idx-1.
    // (ro[0]=0 <= j0 always; ro[num_rows]=nnz > j0 always.)
    int left = 1, right = num_rows;
    while (left < right) {
        int mid = (left + right) >> 1;
        if (ro[mid] <= j0) left = mid + 1; else right = mid;
    }
    int r       = left - 1;
    int row_end = ro[r + 1];

    float sum = 0.0f;

    if (j1 - j0 == ITEMS) {
        // Phase 1: stream sx/sel with nt loads, issue all 16 x-gathers.
        // No dependencies between gathers -> 16 outstanding loads/thread.
        f32x4 s[ITEMS / 4];
        i32x4 c[ITEMS / 4];
        #pragma unroll
        for (int v = 0; v < ITEMS / 4; ++v) {
            s[v] = __builtin_nontemporal_load(
                       reinterpret_cast<const f32x4*>(sx + j0) + v);
            c[v] = __builtin_nontemporal_load(
                       reinterpret_cast<const i32x4*>(sel + j0) + v);
        }
        float p[ITEMS];
        #pragma unroll
        for (int v = 0; v < ITEMS / 4; ++v) {
            #pragma unroll
            for (int k = 0; k < 4; ++k) {
                p[v * 4 + k] = s[v][k] * x[c[v][k]];   // x: cached (L2-resident)
            }
        }
        // Phase 2: row-walk accumulation on registers, atomic flush per row.
        #pragma unroll
        for (int k = 0; k < ITEMS; ++k) {
            int jj = j0 + k;
            while (jj >= row_end) {               // flush row(s); handles empty rows
                if (sum != 0.0f) atomicAdd(&y[r], sum);
                sum = 0.0f;
                ++r;
                row_end = ro[r + 1];
            }
            sum += p[k];
        }
    } else {
        for (int j = j0; j < j1; ++j) {
            while (j >= row_end) {
                if (sum != 0.0f) atomicAdd(&y[r], sum);
                sum = 0.0f;
                ++r;
                row_end = ro[r + 1];
            }
            sum += sx[j] * x[sel[j]];
        }
    }
    if (sum != 0.0f) atomicAdd(&y[r], sum);
}

extern "C" void kernel_launch(void* const* d_in, const int* in_sizes, int n_in,
                              void* d_out, int out_size, void* d_ws, size_t ws_size,
                              hipStream_t stream) {
    const float* sx  = (const float*)d_in[0];
    const float* x   = (const float*)d_in[1];
    // d_in[2] is the zero "y" input — unused; we zero d_out ourselves.
    const int*   sel = (const int*)d_in[3];
    const int*   ro  = (const int*)d_in[4];
    float*       y   = (float*)d_out;

    const int nnz      = in_sizes[0];
    const int num_rows = in_sizes[4] - 1;   // == out_size

    {
        int threads = 256;
        int blocks  = (out_size + threads - 1) / threads;
        zero_out<<<blocks, threads, 0, stream>>>(y, out_size);
    }
    {
        int threads    = 256;
        long long work = ((long long)nnz + ITEMS - 1) / ITEMS;
        int blocks     = (int)((work + threads - 1) / threads);
        spmv_chunk<<<blocks, threads, 0, stream>>>(sx, x, sel, ro, y, nnz, num_rows);
    }
}

// Round 3
// 257.798 us; speedup vs baseline: 1.3426x; 1.1176x over previous
//
#include <hip/hip_runtime.h>

// CSR SpMV: y[r] = sum_{j in [ro[r], ro[r+1])} sx[j] * x[sel[j]]
// NNZ = 32M, ROWS = 1M (+1 offsets), COLS = 1M.
//
// R3 vs R2 (288us, FETCH 232MB == mandatory, 13% HBM peak, VALUBusy 6.5%):
// bound on divergent L2 requests (~63M: 32M x-gathers + ~28M binary-search
// probes + 3M atomics). This round removes the search component:
// block-cooperative row search — each block covers 4096 contiguous nnz
// (~128 rows), does TWO global binary searches (block bounds), coop-loads
// ro[lo..hi+1] into LDS coalesced, then all 256 threads search/walk in LDS.

constexpr int ITEMS     = 16;              // nnz per thread
constexpr int BLOCK     = 256;
constexpr int CHUNK_NNZ = BLOCK * ITEMS;   // 4096 nnz per block
constexpr int SRO_CAP   = 4098;            // LDS row-offset cache (16.4 KB)

typedef float f32x4 __attribute__((ext_vector_type(4)));
typedef int   i32x4 __attribute__((ext_vector_type(4)));

__global__ __launch_bounds__(256) void zero_out(float* __restrict__ y, int n) {
    int i = blockIdx.x * blockDim.x + threadIdx.x;
    if (i < n) y[i] = 0.0f;
}

// upper_bound over ro[1..num_rows], returns row r with ro[r] <= key < ro[r+1]
__device__ __forceinline__ int row_of(const int* __restrict__ ro,
                                      int num_rows, int key) {
    int left = 1, right = num_rows;
    while (left < right) {
        int mid = (left + right) >> 1;
        if (ro[mid] <= key) left = mid + 1; else right = mid;
    }
    return left - 1;
}

__global__ __launch_bounds__(BLOCK) void spmv_chunk(
    const float* __restrict__ sx,
    const float* __restrict__ x,
    const int*   __restrict__ sel,
    const int*   __restrict__ ro,   // length num_rows+1, ro[0]=0, ro[nr]=nnz
    float*       __restrict__ y,
    int nnz, int num_rows)
{
    __shared__ int sro[SRO_CAP];
    __shared__ int s_lo, s_hi;

    const int b  = blockIdx.x;
    const int B0 = b * CHUNK_NNZ;                    // < 2^31, fits int
    const int B1 = min(nnz, B0 + CHUNK_NNZ);

    if (threadIdx.x == 0)         s_lo = row_of(ro, num_rows, B0);
    if (threadIdx.x == BLOCK - 1) s_hi = row_of(ro, num_rows, B1 - 1);
    __syncthreads();

    const int lo = s_lo;
    const int n  = s_hi + 2 - lo;        // cache ro[lo .. hi+1], n entries
    const bool use_lds = (n <= SRO_CAP);
    if (use_lds) {
        for (int i = threadIdx.x; i < n; i += BLOCK) sro[i] = ro[lo + i];
    }
    __syncthreads();

    const int j0 = (b * BLOCK + threadIdx.x) * ITEMS;
    if (j0 >= nnz) return;               // after all barriers — safe
    const int j1 = min(nnz, j0 + ITEMS);

    float sum = 0.0f;

    if (use_lds && j1 - j0 == ITEMS) {
        // Phase 0: row start via LDS binary search (sro[0]<=j0, sro[n-1]>j0)
        int left = 1, right = n - 1;
        while (left < right) {
            int mid = (left + right) >> 1;
            if (sro[mid] <= j0) left = mid + 1; else right = mid;
        }
        int r_local  = left - 1;
        int row_end  = sro[r_local + 1];

        // Phase 1: stream sx/sel with nt loads; issue all 16 x-gathers.
        f32x4 s[ITEMS / 4];
        i32x4 c[ITEMS / 4];
        #pragma unroll
        for (int v = 0; v < ITEMS / 4; ++v) {
            s[v] = __builtin_nontemporal_load(
                       reinterpret_cast<const f32x4*>(sx + j0) + v);
            c[v] = __builtin_nontemporal_load(
                       reinterpret_cast<const i32x4*>(sel + j0) + v);
        }
        float p[ITEMS];
        #pragma unroll
        for (int v = 0; v < ITEMS / 4; ++v) {
            #pragma unroll
            for (int k = 0; k < 4; ++k) {
                p[v * 4 + k] = s[v][k] * x[c[v][k]];   // x: L2-resident
            }
        }

        // Phase 2: row-walk accumulation, offsets from LDS, atomic per row.
        #pragma unroll
        for (int k = 0; k < ITEMS; ++k) {
            int jj = j0 + k;
            while (jj >= row_end) {              // handles empty rows
                if (sum != 0.0f) atomicAdd(&y[lo + r_local], sum);
                sum = 0.0f;
                ++r_local;
                row_end = sro[r_local + 1];
            }
            sum += p[k];
        }
        if (sum != 0.0f) atomicAdd(&y[lo + r_local], sum);
    } else {
        // Fallback (block row-range exceeded LDS cap, or partial tail chunk):
        // per-thread global search + scalar walk. ~never taken for this data.
        int r       = row_of(ro, num_rows, j0);
        int row_end = ro[r + 1];
        for (int j = j0; j < j1; ++j) {
            while (j >= row_end) {
                if (sum != 0.0f) atomicAdd(&y[r], sum);
                sum = 0.0f;
                ++r;
                row_end = ro[r + 1];
            }
            sum += sx[j] * x[sel[j]];
        }
        if (sum != 0.0f) atomicAdd(&y[r], sum);
    }
}

extern "C" void kernel_launch(void* const* d_in, const int* in_sizes, int n_in,
                              void* d_out, int out_size, void* d_ws, size_t ws_size,
                              hipStream_t stream) {
    const float* sx  = (const float*)d_in[0];
    const float* x   = (const float*)d_in[1];
    // d_in[2] is the zero "y" input — unused; we zero d_out ourselves.
    const int*   sel = (const int*)d_in[3];
    const int*   ro  = (const int*)d_in[4];
    float*       y   = (float*)d_out;

    const int nnz      = in_sizes[0];
    const int num_rows = in_sizes[4] - 1;   // == out_size

    {
        int threads = 256;
        int blocks  = (out_size + threads - 1) / threads;
        zero_out<<<blocks, threads, 0, stream>>>(y, out_size);
    }
    {
        int blocks = (nnz + CHUNK_NNZ - 1) / CHUNK_NNZ;
        spmv_chunk<<<blocks, BLOCK, 0, stream>>>(sx, x, sel, ro, y, nnz, num_rows);
    }
}